// Round 1
// 19382.413 us; speedup vs baseline: 1.0279x; 1.0279x over previous
//
#include <hip/hip_runtime.h>

#define HDIM 96
#define G4   384
#define LSEQ 32768
#define BATCH 8
#define TCH   1024
#define NCH   (LSEQ / TCH)

#define L2E  1.4426950408889634f
#define SNEG (-L2E)        /* sigmoid gates: exp(-x) = exp2(SNEG*x) */
#define SPOS (2.0f * L2E)  /* tanh gates:    exp(2x) = exp2(SPOS*x) */

// Gate values arrive PRE-SCALED (weights multiplied at load time), so
// activations are a raw v_exp_f32 with no argument multiply.
__device__ __forceinline__ float sigm2_(float x) {   // x = SNEG * gate
    return __builtin_amdgcn_rcpf(1.f + __builtin_amdgcn_exp2f(x));
}
__device__ __forceinline__ float tanh2_(float x) {   // x = SPOS * gate
    return fmaf(-2.f, __builtin_amdgcn_rcpf(1.f + __builtin_amdgcn_exp2f(x)), 1.f);
}
__device__ __forceinline__ float tanh_(float x) {    // raw argument (c state)
    return fmaf(-2.f, __builtin_amdgcn_rcpf(1.f + __builtin_amdgcn_exp2f(SPOS * x)), 1.f);
}

// 8-lane butterfly sum on the VALU pipe (DPP), zero DS-pipe usage.
#define DPPSTEP(v, CTRL) { \
    int t_ = __builtin_amdgcn_update_dpp(0, __float_as_int(v), CTRL, 0xF, 0xF, true); \
    v += __int_as_float(t_); }
#define RED8(v) DPPSTEP(v, 0xB1) DPPSTEP(v, 0x4E) DPPSTEP(v, 0x141)

// Lite barrier: LDS ordering only. Global stores/loads stay in flight
// (the implicit vmcnt(0) drain in __syncthreads was ~half the step time).
// Single asm blob + memory clobber: nothing can be scheduled inside it and
// no memory op can be hoisted across it.
#define BARL() asm volatile("s_waitcnt lgkmcnt(0)\n\ts_barrier" ::: "memory")

#define PIN4x3(A,B,C) asm volatile("" : \
  "+v"(A.x),"+v"(A.y),"+v"(A.z),"+v"(A.w), \
  "+v"(B.x),"+v"(B.y),"+v"(B.z),"+v"(B.w), \
  "+v"(C.x),"+v"(C.y),"+v"(C.z),"+v"(C.w));

#define SC4(V, S) { V.x *= (S); V.y *= (S); V.z *= (S); V.w *= (S); }

// Thread owns all 4 gate rows of element e x cols [12s, 12s+12).
// Weights pre-scaled per gate for exp2-direct activations.
#define WLOADPIN(W) \
    const float4* pI = reinterpret_cast<const float4*>((W) + (size_t)e        * HDIM + 12*s); \
    const float4* pF = reinterpret_cast<const float4*>((W) + (size_t)(96 + e) * HDIM + 12*s); \
    const float4* pG = reinterpret_cast<const float4*>((W) + (size_t)(192+ e) * HDIM + 12*s); \
    const float4* pO = reinterpret_cast<const float4*>((W) + (size_t)(288+ e) * HDIM + 12*s); \
    float4 wI0=pI[0], wI1=pI[1], wI2=pI[2]; \
    float4 wF0=pF[0], wF1=pF[1], wF2=pF[2]; \
    float4 wG0=pG[0], wG1=pG[1], wG2=pG[2]; \
    float4 wO0=pO[0], wO1=pO[1], wO2=pO[2]; \
    SC4(wI0,SNEG) SC4(wI1,SNEG) SC4(wI2,SNEG) \
    SC4(wF0,SNEG) SC4(wF1,SNEG) SC4(wF2,SNEG) \
    SC4(wG0,SPOS) SC4(wG1,SPOS) SC4(wG2,SPOS) \
    SC4(wO0,SNEG) SC4(wO1,SNEG) SC4(wO2,SNEG) \
    PIN4x3(wI0,wI1,wI2) PIN4x3(wF0,wF1,wF2) PIN4x3(wG0,wG1,wG2) PIN4x3(wO0,wO1,wO2)

#define MVK(n, hv) \
  gi=fmaf(wI##n.x,hv.x,gi); gi=fmaf(wI##n.y,hv.y,gi); gi=fmaf(wI##n.z,hv.z,gi); gi=fmaf(wI##n.w,hv.w,gi); \
  gf=fmaf(wF##n.x,hv.x,gf); gf=fmaf(wF##n.y,hv.y,gf); gf=fmaf(wF##n.z,hv.z,gf); gf=fmaf(wF##n.w,hv.w,gf); \
  gg=fmaf(wG##n.x,hv.x,gg); gg=fmaf(wG##n.y,hv.y,gg); gg=fmaf(wG##n.z,hv.z,gg); gg=fmaf(wG##n.w,hv.w,gg); \
  go=fmaf(wO##n.x,hv.x,go); go=fmaf(wO##n.y,hv.y,go); go=fmaf(wO##n.z,hv.z,go); go=fmaf(wO##n.w,hv.w,go);

#define WAIT_GE(PTR, VAL) \
    while (__hip_atomic_load((PTR), __ATOMIC_ACQUIRE, __HIP_MEMORY_SCOPE_AGENT) < (VAL)) \
        __builtin_amdgcn_s_sleep(2);

#define SIGNAL(PTR, VAL) \
    __hip_atomic_store((PTR), (VAL), __ATOMIC_RELEASE, __HIP_MEMORY_SCOPE_AGENT);

__global__ void init_flags(int* flags) {
    if (threadIdx.x < 64) flags[threadIdx.x] = 0;
}

// ---------------------------------------------------------------------------
// 32 blocks, 4 roles:
//   0..7   producer : L0 scan (DPP core) -> h0buf, flag0 per TCH chunk
//   8..15  xp worker: flag0 -> xp ring depth 2 in (t,e,gate)-float4, flag1
//   16..23 consumer : flag1 -> L1 scan (DPP core) -> h1 ring, flag2
//   24..31 head     : flag2 -> out, flag3 (h1 slot reuse)
// Per-step sync is BARL() (lgkmcnt-only barrier): the LDS h handoff is the
// only cross-wave dep; global stores drain only at chunk boundaries, where
// the full __threadfence + __syncthreads + SIGNAL protocol is unchanged.
// ---------------------------------------------------------------------------
__global__ void __launch_bounds__(768)
__attribute__((amdgpu_waves_per_eu(3, 3)))
lstm_pipe(const float* __restrict__ x,
          const float* __restrict__ Wih0, const float* __restrict__ Whh0, const float* __restrict__ b0v,
          const float* __restrict__ Wih1, const float* __restrict__ Whh1, const float* __restrict__ b1v,
          const float* __restrict__ h0v,  const float* __restrict__ c0v,
          const float* __restrict__ headw,const float* __restrict__ headb,
          float* __restrict__ h0buf, float* __restrict__ xpbuf, float* __restrict__ h1buf,
          int* flags, float* __restrict__ out)
{
    const int tid  = threadIdx.x;
    const int lane = tid & 63;
    const int e    = tid >> 3;     // element 0..95
    const int s    = tid & 7;      // 12-col segment 0..7
    const bool w0l = ((lane & 7) == 0);

    int* flag0 = flags;
    int* flag1 = flags + 8;
    int* flag2 = flags + 16;
    int* flag3 = flags + 24;

    __shared__ __align__(16) float hs[2 * HDIM];
    __shared__ __align__(16) float h_sh[32 * HDIM];
    __shared__ float ph_sh[2 * G4];          // tt-parity double buffer

    const int role = blockIdx.x >> 3;
    const int bidx = blockIdx.x & 7;

    if (role == 0) {
        // =================== producer: L0 scan ===================
        WLOADPIN(Whh0)
        // input weights + bias folded into accumulator INIT: pre-scaled by
        // gate-const and by 1/8 (8-lane butterfly sums 8 identical copies
        // back to the full value, exactly — powers of two).
        const float wiI = Wih0[e]      * (SNEG * 0.125f);
        const float wiF = Wih0[96 + e] * (SNEG * 0.125f);
        const float wiG = Wih0[192+ e] * (SPOS * 0.125f);
        const float wiO = Wih0[288+ e] * (SNEG * 0.125f);
        const float bbI = b0v[e]       * (SNEG * 0.125f);
        const float bbF = b0v[96 + e]  * (SNEG * 0.125f);
        const float bbG = b0v[192+ e]  * (SPOS * 0.125f);
        const float bbO = b0v[288+ e]  * (SNEG * 0.125f);

        float cU = c0v[e];
        if (w0l) hs[e] = h0v[e];
        __syncthreads();

        const float* xb  = x + (size_t)bidx * LSEQ;
        float*       hob = h0buf + (size_t)bidx * LSEQ * HDIM;
        float xt = xb[0];
        int rOff = 0;

#pragma unroll 1
        for (int t = 0; t < LSEQ; ++t) {
            int tn = (t + 1 < LSEQ) ? t + 1 : LSEQ - 1;
            float xnext = xb[tn];

            const float4* hp = reinterpret_cast<const float4*>(hs + rOff + 12 * s);
            float4 hv0 = hp[0], hv1 = hp[1], hv2 = hp[2];

            float gi = fmaf(wiI, xt, bbI);
            float gf = fmaf(wiF, xt, bbF);
            float gg = fmaf(wiG, xt, bbG);
            float go = fmaf(wiO, xt, bbO);
            MVK(0, hv0) MVK(1, hv1) MVK(2, hv2)
            RED8(gi) RED8(gf) RED8(gg) RED8(go)

            float si = sigm2_(gi), sf = sigm2_(gf), tg = tanh2_(gg), so = sigm2_(go);
            cU = fmaf(sf, cU, si * tg);
            float hN = so * tanh_(cU);

            if (w0l) {
                hs[(rOff ^ HDIM) + e] = hN;
                hob[(size_t)t * HDIM + e] = hN;   // stays in flight past BARL
            }
            rOff ^= HDIM;
            xt = xnext;

            if (((t + 1) & (TCH - 1)) == 0) {
                __threadfence();                  // full drain (chunk publish)
                __syncthreads();
                if (tid == 0) SIGNAL(&flag0[bidx], (t + 1) / TCH)
            }
            BARL();
        }
    } else if (role == 1) {
        // =================== xp worker ===================
        const bool halfx = (tid >= G4);
        const int  g     = halfx ? tid - G4 : tid;
        const int  dstoff = (g % 96) * 4 + (g / 96);   // (e,gate) float4 layout
        const float gsc  = ((g / 96) == 2) ? SPOS : SNEG;  // pre-scale gates here
        const float4* Wxp = reinterpret_cast<const float4*>(Wih1 + (size_t)g * HDIM + (halfx ? 48 : 0));
        const float xbias = halfx ? 0.f : b1v[g] * gsc;

        float4 q0=Wxp[0],q1=Wxp[1],q2=Wxp[2],q3=Wxp[3],q4=Wxp[4],q5=Wxp[5],
               q6=Wxp[6],q7=Wxp[7],q8=Wxp[8],q9=Wxp[9],q10=Wxp[10],q11=Wxp[11];
        SC4(q0,gsc) SC4(q1,gsc) SC4(q2,gsc)  SC4(q3,gsc) SC4(q4,gsc)  SC4(q5,gsc)
        SC4(q6,gsc) SC4(q7,gsc) SC4(q8,gsc)  SC4(q9,gsc) SC4(q10,gsc) SC4(q11,gsc)
        PIN4x3(q0,q1,q2) PIN4x3(q3,q4,q5) PIN4x3(q6,q7,q8) PIN4x3(q9,q10,q11)

        const float* hsrcB = h0buf + (size_t)bidx * LSEQ * HDIM;

#pragma unroll 1
        for (int k = 0; k < NCH; ++k) {
            if (tid == 0) {
                WAIT_GE(&flag0[bidx], k + 1)
                if (k >= 2) WAIT_GE(&flag2[bidx], k - 1)
            }
            __syncthreads();
            __threadfence();

            const float* hsrc = hsrcB + (size_t)k * TCH * HDIM;
            float* xpd = xpbuf + ((size_t)bidx * 2 + (k & 1)) * TCH * G4;

#pragma unroll 1
            for (int t0 = 0; t0 < TCH; t0 += 32) {
                // 32*96 floats = exactly one float4 per thread
                reinterpret_cast<float4*>(h_sh)[tid] =
                    reinterpret_cast<const float4*>(hsrc + (size_t)t0 * HDIM)[tid];
                BARL();
#pragma unroll 1
                for (int tt = 0; tt < 32; ++tt) {
                    const float4* h4 = reinterpret_cast<const float4*>(
                        h_sh + tt * HDIM + (halfx ? 48 : 0));
                    float a0 = xbias, a1 = 0.f, a2 = 0.f, a3 = 0.f;
                    float4 hv;
                    hv=h4[0];  a0=fmaf(q0.x, hv.x,a0); a1=fmaf(q0.y, hv.y,a1); a2=fmaf(q0.z, hv.z,a2); a3=fmaf(q0.w, hv.w,a3);
                    hv=h4[1];  a0=fmaf(q1.x, hv.x,a0); a1=fmaf(q1.y, hv.y,a1); a2=fmaf(q1.z, hv.z,a2); a3=fmaf(q1.w, hv.w,a3);
                    hv=h4[2];  a0=fmaf(q2.x, hv.x,a0); a1=fmaf(q2.y, hv.y,a1); a2=fmaf(q2.z, hv.z,a2); a3=fmaf(q2.w, hv.w,a3);
                    hv=h4[3];  a0=fmaf(q3.x, hv.x,a0); a1=fmaf(q3.y, hv.y,a1); a2=fmaf(q3.z, hv.z,a2); a3=fmaf(q3.w, hv.w,a3);
                    hv=h4[4];  a0=fmaf(q4.x, hv.x,a0); a1=fmaf(q4.y, hv.y,a1); a2=fmaf(q4.z, hv.z,a2); a3=fmaf(q4.w, hv.w,a3);
                    hv=h4[5];  a0=fmaf(q5.x, hv.x,a0); a1=fmaf(q5.y, hv.y,a1); a2=fmaf(q5.z, hv.z,a2); a3=fmaf(q5.w, hv.w,a3);
                    hv=h4[6];  a0=fmaf(q6.x, hv.x,a0); a1=fmaf(q6.y, hv.y,a1); a2=fmaf(q6.z, hv.z,a2); a3=fmaf(q6.w, hv.w,a3);
                    hv=h4[7];  a0=fmaf(q7.x, hv.x,a0); a1=fmaf(q7.y, hv.y,a1); a2=fmaf(q7.z, hv.z,a2); a3=fmaf(q7.w, hv.w,a3);
                    hv=h4[8];  a0=fmaf(q8.x, hv.x,a0); a1=fmaf(q8.y, hv.y,a1); a2=fmaf(q8.z, hv.z,a2); a3=fmaf(q8.w, hv.w,a3);
                    hv=h4[9];  a0=fmaf(q9.x, hv.x,a0); a1=fmaf(q9.y, hv.y,a1); a2=fmaf(q9.z, hv.z,a2); a3=fmaf(q9.w, hv.w,a3);
                    hv=h4[10]; a0=fmaf(q10.x,hv.x,a0); a1=fmaf(q10.y,hv.y,a1); a2=fmaf(q10.z,hv.z,a2); a3=fmaf(q10.w,hv.w,a3);
                    hv=h4[11]; a0=fmaf(q11.x,hv.x,a0); a1=fmaf(q11.y,hv.y,a1); a2=fmaf(q11.z,hv.z,a2); a3=fmaf(q11.w,hv.w,a3);
                    float part = (a0 + a1) + (a2 + a3);
                    float* ph2 = ph_sh + ((tt & 1) ? G4 : 0);   // parity dbuf:
                    if (halfx) ph2[g] = part;                   // 1 barrier/tt
                    BARL();
                    if (!halfx) xpd[(size_t)(t0 + tt) * G4 + dstoff] = part + ph2[g];
                }
                BARL();   // protect h_sh + ph slot reuse before next stage
            }
            __threadfence();
            __syncthreads();
            if (tid == 0) SIGNAL(&flag1[bidx], k + 1)
        }
    } else if (role == 2) {
        // =================== consumer: L1 scan ===================
        WLOADPIN(Whh1)

        float cU = c0v[HDIM + e];
        if (w0l) hs[e] = h0v[HDIM + e];
        __syncthreads();
        int rOff = 0;

#pragma unroll 1
        for (int k = 0; k < NCH; ++k) {
            if (tid == 0) {
                WAIT_GE(&flag1[bidx], k + 1)
                if (k >= 2) WAIT_GE(&flag3[bidx], k - 1)
            }
            __syncthreads();
            __threadfence();

            const float4* xq  = reinterpret_cast<const float4*>(
                xpbuf + ((size_t)bidx * 2 + (k & 1)) * TCH * G4) + e;
            float* h1c = h1buf + ((size_t)bidx * 2 + (k & 1)) * TCH * HDIM;

            float4 xpA = xq[0];           // depth-2 prefetch: xp ring may be
            float4 xpB = xq[HDIM];        // on another XCD (L3/HBM latency)

#pragma unroll 1
            for (int t = 0; t < TCH; ++t) {
                int tn2 = (t + 2 < TCH) ? t + 2 : TCH - 1;
                float4 xpN = xq[(size_t)tn2 * HDIM];

                const float4* hp = reinterpret_cast<const float4*>(hs + rOff + 12 * s);
                float4 hv0 = hp[0], hv1 = hp[1], hv2 = hp[2];

                float gi = 0.f, gf = 0.f, gg = 0.f, go = 0.f;
                MVK(0, hv0) MVK(1, hv1) MVK(2, hv2)
                RED8(gi) RED8(gf) RED8(gg) RED8(go)
                // xp (bias folded, pre-scaled at producer) added post-reduction
                gi += xpA.x; gf += xpA.y; gg += xpA.z; go += xpA.w;

                float si = sigm2_(gi), sf = sigm2_(gf), tg = tanh2_(gg), so = sigm2_(go);
                cU = fmaf(sf, cU, si * tg);
                float hN = so * tanh_(cU);

                if (w0l) {
                    hs[(rOff ^ HDIM) + e] = hN;
                    h1c[(size_t)t * HDIM + e] = hN;
                }
                rOff ^= HDIM;
                xpA = xpB; xpB = xpN;
                BARL();
            }
            __threadfence();
            __syncthreads();
            if (tid == 0) SIGNAL(&flag2[bidx], k + 1)
        }
    } else {
        // =================== head ===================
        const float hb = headb[0];
        float4 wv[24];
#pragma unroll
        for (int j = 0; j < 24; ++j) wv[j] = reinterpret_cast<const float4*>(headw)[j];

#pragma unroll 1
        for (int k = 0; k < NCH; ++k) {
            if (tid == 0) WAIT_GE(&flag2[bidx], k + 1)
            __syncthreads();
            __threadfence();

            const float* h1c = h1buf + ((size_t)bidx * 2 + (k & 1)) * TCH * HDIM;
            for (int t = tid; t < TCH; t += 768) {
                const float4* hp = reinterpret_cast<const float4*>(h1c + (size_t)t * HDIM);
                float s2 = 0.f;
#pragma unroll
                for (int j = 0; j < 24; ++j) {
                    float4 a = hp[j], b = wv[j];
                    s2 = fmaf(a.x, b.x, s2); s2 = fmaf(a.y, b.y, s2);
                    s2 = fmaf(a.z, b.z, s2); s2 = fmaf(a.w, b.w, s2);
                }
                out[(size_t)bidx * LSEQ + (size_t)k * TCH + t] = s2 + hb;
            }
            __threadfence();
            __syncthreads();
            if (tid == 0) SIGNAL(&flag3[bidx], k + 1)
        }
    }
}

// ---------------------------------------------------------------------------
extern "C" void kernel_launch(void* const* d_in, const int* in_sizes, int n_in,
                              void* d_out, int out_size, void* d_ws, size_t ws_size,
                              hipStream_t stream)
{
    const float* x     = (const float*)d_in[0];
    const float* Wih0  = (const float*)d_in[1];
    const float* Whh0  = (const float*)d_in[2];
    const float* b0    = (const float*)d_in[3];
    const float* Wih1  = (const float*)d_in[4];
    const float* Whh1  = (const float*)d_in[5];
    const float* b1    = (const float*)d_in[6];
    const float* h0    = (const float*)d_in[7];
    const float* c0    = (const float*)d_in[8];
    const float* headw = (const float*)d_in[9];
    const float* headb = (const float*)d_in[10];
    float* out = (float*)d_out;

    char* ws = (char*)d_ws;
    const size_t h0bytes = (size_t)BATCH * LSEQ * HDIM * sizeof(float);    // 100.7 MB
    const size_t xpbytes = (size_t)BATCH * 2 * TCH * G4 * sizeof(float);   // 25.2 MB
    const size_t h1bytes = (size_t)BATCH * 2 * TCH * HDIM * sizeof(float); // 6.3 MB

    float* h0buf = (float*)ws;
    float* xpbuf = (float*)(ws + h0bytes);
    float* h1buf = (float*)(ws + h0bytes + xpbytes);
    int*   flags = (int*)  (ws + h0bytes + xpbytes + h1bytes);

    init_flags<<<1, 64, 0, stream>>>(flags);
    lstm_pipe<<<32, 768, 0, stream>>>(x, Wih0, Whh0, b0, Wih1, Whh1, b1,
                                      h0, c0, headw, headb,
                                      h0buf, xpbuf, h1buf, flags, out);
}

// Round 2
// 16645.261 us; speedup vs baseline: 1.1969x; 1.1644x over previous
//
#include <hip/hip_runtime.h>

#define HDIM 96
#define G4   384
#define LSEQ 32768
#define BATCH 8
#define TCH   1024
#define NCH   (LSEQ / TCH)

#define L2E  1.4426950408889634f
#define SNEG (-L2E)        /* sigmoid gates: exp(-x) = exp2(SNEG*x) */
#define SPOS (2.0f * L2E)  /* tanh gates:    exp(2x) = exp2(SPOS*x) */

// Gate values arrive PRE-SCALED (weights multiplied at load time), so
// activations are a raw v_exp_f32 with no argument multiply.
__device__ __forceinline__ float sigm2_(float x) {   // x = SNEG * gate
    return __builtin_amdgcn_rcpf(1.f + __builtin_amdgcn_exp2f(x));
}
__device__ __forceinline__ float tanh2_(float x) {   // x = SPOS * gate
    return fmaf(-2.f, __builtin_amdgcn_rcpf(1.f + __builtin_amdgcn_exp2f(x)), 1.f);
}
__device__ __forceinline__ float tanh_(float x) {    // raw argument (c state)
    return fmaf(-2.f, __builtin_amdgcn_rcpf(1.f + __builtin_amdgcn_exp2f(SPOS * x)), 1.f);
}

// 8-lane butterfly sum on the VALU pipe (DPP), zero DS-pipe usage.
#define DPPSTEP(v, CTRL) { \
    int t_ = __builtin_amdgcn_update_dpp(0, __float_as_int(v), CTRL, 0xF, 0xF, true); \
    v += __int_as_float(t_); }
#define RED8(v) DPPSTEP(v, 0xB1) DPPSTEP(v, 0x4E) DPPSTEP(v, 0x141)

// Lite barrier: LDS ordering only; global ops stay in flight.
#define BARL() asm volatile("s_waitcnt lgkmcnt(0)\n\ts_barrier" ::: "memory")

#define PIN4x3(A,B,C) asm volatile("" : \
  "+v"(A.x),"+v"(A.y),"+v"(A.z),"+v"(A.w), \
  "+v"(B.x),"+v"(B.y),"+v"(B.z),"+v"(B.w), \
  "+v"(C.x),"+v"(C.y),"+v"(C.z),"+v"(C.w));

#define SC4(V, S) { V.x *= (S); V.y *= (S); V.z *= (S); V.w *= (S); }

// Thread owns all 4 gate rows of element e x cols [12s, 12s+12).
// Weights pre-scaled per gate for exp2-direct activations.
#define WLOADPIN(W) \
    const float4* pI = reinterpret_cast<const float4*>((W) + (size_t)e        * HDIM + 12*s); \
    const float4* pF = reinterpret_cast<const float4*>((W) + (size_t)(96 + e) * HDIM + 12*s); \
    const float4* pG = reinterpret_cast<const float4*>((W) + (size_t)(192+ e) * HDIM + 12*s); \
    const float4* pO = reinterpret_cast<const float4*>((W) + (size_t)(288+ e) * HDIM + 12*s); \
    float4 wI0=pI[0], wI1=pI[1], wI2=pI[2]; \
    float4 wF0=pF[0], wF1=pF[1], wF2=pF[2]; \
    float4 wG0=pG[0], wG1=pG[1], wG2=pG[2]; \
    float4 wO0=pO[0], wO1=pO[1], wO2=pO[2]; \
    SC4(wI0,SNEG) SC4(wI1,SNEG) SC4(wI2,SNEG) \
    SC4(wF0,SNEG) SC4(wF1,SNEG) SC4(wF2,SNEG) \
    SC4(wG0,SPOS) SC4(wG1,SPOS) SC4(wG2,SPOS) \
    SC4(wO0,SNEG) SC4(wO1,SNEG) SC4(wO2,SNEG) \
    PIN4x3(wI0,wI1,wI2) PIN4x3(wF0,wF1,wF2) PIN4x3(wG0,wG1,wG2) PIN4x3(wO0,wO1,wO2)

#define MVK(n, hv) \
  gi=fmaf(wI##n.x,hv.x,gi); gi=fmaf(wI##n.y,hv.y,gi); gi=fmaf(wI##n.z,hv.z,gi); gi=fmaf(wI##n.w,hv.w,gi); \
  gf=fmaf(wF##n.x,hv.x,gf); gf=fmaf(wF##n.y,hv.y,gf); gf=fmaf(wF##n.z,hv.z,gf); gf=fmaf(wF##n.w,hv.w,gf); \
  gg=fmaf(wG##n.x,hv.x,gg); gg=fmaf(wG##n.y,hv.y,gg); gg=fmaf(wG##n.z,hv.z,gg); gg=fmaf(wG##n.w,hv.w,gg); \
  go=fmaf(wO##n.x,hv.x,go); go=fmaf(wO##n.y,hv.y,go); go=fmaf(wO##n.z,hv.z,go); go=fmaf(wO##n.w,hv.w,go);

#define WAIT_GE(PTR, VAL) \
    while (__hip_atomic_load((PTR), __ATOMIC_ACQUIRE, __HIP_MEMORY_SCOPE_AGENT) < (VAL)) \
        __builtin_amdgcn_s_sleep(2);

#define SIGNAL(PTR, VAL) \
    __hip_atomic_store((PTR), (VAL), __ATOMIC_RELEASE, __HIP_MEMORY_SCOPE_AGENT);

__global__ void init_flags(int* flags) {
    if (threadIdx.x < 64) flags[threadIdx.x] = 0;
}

// One LSTM step, role 0. RO = LDS read offset (0/96, compile-time).
// gg reduced first so its exp2 (longest chain: g->c->tanh->h) issues while
// the other butterflies are still in flight.
#define STEP0(RO, XT) { \
    const float4* hp = reinterpret_cast<const float4*>(hs + (RO) + 12 * s); \
    float4 hv0 = hp[0], hv1 = hp[1], hv2 = hp[2]; \
    float gi = fmaf(wiI, (XT), bbI); \
    float gf = fmaf(wiF, (XT), bbF); \
    float gg = fmaf(wiG, (XT), bbG); \
    float go = fmaf(wiO, (XT), bbO); \
    MVK(0, hv0) MVK(1, hv1) MVK(2, hv2) \
    RED8(gg) float tg = tanh2_(gg); \
    RED8(gf) RED8(gi) \
    float sf = sigm2_(gf), si = sigm2_(gi); \
    RED8(go) float so = sigm2_(go); \
    cU = fmaf(sf, cU, si * tg); \
    float hN = so * tanh_(cU); \
    if (w0l) { hs[((RO) ^ HDIM) + e] = hN; *hobp = hN; } \
    hobp += HDIM; }

// One LSTM step, role 2. xp (pre-scaled by gate-const/8 at role 1) folds
// into the accumulator init; the 8-lane butterfly restores the full value.
#define STEP2(RO, XPV) { \
    const float4* hp = reinterpret_cast<const float4*>(hs + (RO) + 12 * s); \
    float4 hv0 = hp[0], hv1 = hp[1], hv2 = hp[2]; \
    float gi = (XPV).x, gf = (XPV).y, gg = (XPV).z, go = (XPV).w; \
    MVK(0, hv0) MVK(1, hv1) MVK(2, hv2) \
    RED8(gg) float tg = tanh2_(gg); \
    RED8(gf) RED8(gi) \
    float sf = sigm2_(gf), si = sigm2_(gi); \
    RED8(go) float so = sigm2_(go); \
    cU = fmaf(sf, cU, si * tg); \
    float hN = so * tanh_(cU); \
    if (w0l) { hs[((RO) ^ HDIM) + e] = hN; *h1p = hN; } \
    h1p += HDIM; }

// ---------------------------------------------------------------------------
// 32 blocks, 4 roles:
//   0..7   producer : L0 scan (DPP core, x8 unroll) -> h0buf, flag0 per chunk
//   8..15  xp worker: flag0 -> xp ring depth 2 in (t,e,gate)-float4, flag1
//   16..23 consumer : flag1 -> L1 scan (DPP core, x8 unroll) -> h1 ring, flag2
//   24..31 head     : flag2 -> out, flag3 (h1 slot reuse)
// Scans unrolled x8: static LDS offsets (no rOff toggle), float4 x loads
// (1 per 4 steps), static xp addressing (no per-step 64-bit mul), one
// chunk-boundary check per 8 steps.
// ---------------------------------------------------------------------------
__global__ void __launch_bounds__(768)
__attribute__((amdgpu_waves_per_eu(3, 3)))
lstm_pipe(const float* __restrict__ x,
          const float* __restrict__ Wih0, const float* __restrict__ Whh0, const float* __restrict__ b0v,
          const float* __restrict__ Wih1, const float* __restrict__ Whh1, const float* __restrict__ b1v,
          const float* __restrict__ h0v,  const float* __restrict__ c0v,
          const float* __restrict__ headw,const float* __restrict__ headb,
          float* __restrict__ h0buf, float* __restrict__ xpbuf, float* __restrict__ h1buf,
          int* flags, float* __restrict__ out)
{
    const int tid  = threadIdx.x;
    const int lane = tid & 63;
    const int e    = tid >> 3;     // element 0..95
    const int s    = tid & 7;      // 12-col segment 0..7
    const bool w0l = ((lane & 7) == 0);

    int* flag0 = flags;
    int* flag1 = flags + 8;
    int* flag2 = flags + 16;
    int* flag3 = flags + 24;

    __shared__ __align__(16) float hs[2 * HDIM];
    __shared__ __align__(16) float h_sh[32 * HDIM];
    __shared__ float ph_sh[2 * G4];          // tt-parity double buffer

    const int role = blockIdx.x >> 3;
    const int bidx = blockIdx.x & 7;

    if (role == 0) {
        // =================== producer: L0 scan ===================
        WLOADPIN(Whh0)
        // input weights + bias folded into accumulator INIT, pre-scaled by
        // gate-const and 1/8 (butterfly sums 8 identical copies — exact).
        const float wiI = Wih0[e]      * (SNEG * 0.125f);
        const float wiF = Wih0[96 + e] * (SNEG * 0.125f);
        const float wiG = Wih0[192+ e] * (SPOS * 0.125f);
        const float wiO = Wih0[288+ e] * (SNEG * 0.125f);
        const float bbI = b0v[e]       * (SNEG * 0.125f);
        const float bbF = b0v[96 + e]  * (SNEG * 0.125f);
        const float bbG = b0v[192+ e]  * (SPOS * 0.125f);
        const float bbO = b0v[288+ e]  * (SNEG * 0.125f);

        float cU = c0v[e];
        if (w0l) hs[e] = h0v[e];
        __syncthreads();

        const float* xb  = x + (size_t)bidx * LSEQ;
        float*       hobp = h0buf + (size_t)bidx * LSEQ * HDIM + e;

        float4 xA = *reinterpret_cast<const float4*>(xb);   // t = 0..3

#pragma unroll 1
        for (int gI = 0; gI < LSEQ / 8; ++gI) {
            float4 xB = *reinterpret_cast<const float4*>(xb + gI * 8 + 4);
            STEP0(0,    xA.x) BARL();
            STEP0(HDIM, xA.y) BARL();
            STEP0(0,    xA.z) BARL();
            STEP0(HDIM, xA.w) BARL();
            float4 xAn = *reinterpret_cast<const float4*>(
                xb + (((gI + 1) * 8 < LSEQ) ? (gI + 1) * 8 : LSEQ - 8));
            STEP0(0,    xB.x) BARL();
            STEP0(HDIM, xB.y) BARL();
            STEP0(0,    xB.z) BARL();
            STEP0(HDIM, xB.w)
            xA = xAn;
            if (((gI + 1) & 127) == 0) {      // t+1 = 8(gI+1) ≡ 0 mod TCH
                __threadfence();
                __syncthreads();
                if (tid == 0) SIGNAL(&flag0[bidx], (gI + 1) >> 7)
            } else {
                BARL();
            }
        }
    } else if (role == 1) {
        // =================== xp worker ===================
        const bool halfx = (tid >= G4);
        const int  g     = halfx ? tid - G4 : tid;
        const int  dstoff = (g % 96) * 4 + (g / 96);   // (e,gate) float4 layout
        // gate-const AND 1/8: role 2 folds xp into the accumulator init and
        // the 8-lane butterfly multiplies it back (exact, power of two).
        const float gsc  = (((g / 96) == 2) ? SPOS : SNEG) * 0.125f;
        const float4* Wxp = reinterpret_cast<const float4*>(Wih1 + (size_t)g * HDIM + (halfx ? 48 : 0));
        const float xbias = halfx ? 0.f : b1v[g] * gsc;

        float4 q0=Wxp[0],q1=Wxp[1],q2=Wxp[2],q3=Wxp[3],q4=Wxp[4],q5=Wxp[5],
               q6=Wxp[6],q7=Wxp[7],q8=Wxp[8],q9=Wxp[9],q10=Wxp[10],q11=Wxp[11];
        SC4(q0,gsc) SC4(q1,gsc) SC4(q2,gsc)  SC4(q3,gsc) SC4(q4,gsc)  SC4(q5,gsc)
        SC4(q6,gsc) SC4(q7,gsc) SC4(q8,gsc)  SC4(q9,gsc) SC4(q10,gsc) SC4(q11,gsc)
        PIN4x3(q0,q1,q2) PIN4x3(q3,q4,q5) PIN4x3(q6,q7,q8) PIN4x3(q9,q10,q11)

        const float* hsrcB = h0buf + (size_t)bidx * LSEQ * HDIM;

#pragma unroll 1
        for (int k = 0; k < NCH; ++k) {
            if (tid == 0) {
                WAIT_GE(&flag0[bidx], k + 1)
                if (k >= 2) WAIT_GE(&flag2[bidx], k - 1)
            }
            __syncthreads();
            __threadfence();

            const float* hsrc = hsrcB + (size_t)k * TCH * HDIM;
            float* xpd = xpbuf + ((size_t)bidx * 2 + (k & 1)) * TCH * G4;

#pragma unroll 1
            for (int t0 = 0; t0 < TCH; t0 += 32) {
                // 32*96 floats = exactly one float4 per thread
                reinterpret_cast<float4*>(h_sh)[tid] =
                    reinterpret_cast<const float4*>(hsrc + (size_t)t0 * HDIM)[tid];
                BARL();
#pragma unroll 1
                for (int tt = 0; tt < 32; ++tt) {
                    const float4* h4 = reinterpret_cast<const float4*>(
                        h_sh + tt * HDIM + (halfx ? 48 : 0));
                    float a0 = xbias, a1 = 0.f, a2 = 0.f, a3 = 0.f;
                    float4 hv;
                    hv=h4[0];  a0=fmaf(q0.x, hv.x,a0); a1=fmaf(q0.y, hv.y,a1); a2=fmaf(q0.z, hv.z,a2); a3=fmaf(q0.w, hv.w,a3);
                    hv=h4[1];  a0=fmaf(q1.x, hv.x,a0); a1=fmaf(q1.y, hv.y,a1); a2=fmaf(q1.z, hv.z,a2); a3=fmaf(q1.w, hv.w,a3);
                    hv=h4[2];  a0=fmaf(q2.x, hv.x,a0); a1=fmaf(q2.y, hv.y,a1); a2=fmaf(q2.z, hv.z,a2); a3=fmaf(q2.w, hv.w,a3);
                    hv=h4[3];  a0=fmaf(q3.x, hv.x,a0); a1=fmaf(q3.y, hv.y,a1); a2=fmaf(q3.z, hv.z,a2); a3=fmaf(q3.w, hv.w,a3);
                    hv=h4[4];  a0=fmaf(q4.x, hv.x,a0); a1=fmaf(q4.y, hv.y,a1); a2=fmaf(q4.z, hv.z,a2); a3=fmaf(q4.w, hv.w,a3);
                    hv=h4[5];  a0=fmaf(q5.x, hv.x,a0); a1=fmaf(q5.y, hv.y,a1); a2=fmaf(q5.z, hv.z,a2); a3=fmaf(q5.w, hv.w,a3);
                    hv=h4[6];  a0=fmaf(q6.x, hv.x,a0); a1=fmaf(q6.y, hv.y,a1); a2=fmaf(q6.z, hv.z,a2); a3=fmaf(q6.w, hv.w,a3);
                    hv=h4[7];  a0=fmaf(q7.x, hv.x,a0); a1=fmaf(q7.y, hv.y,a1); a2=fmaf(q7.z, hv.z,a2); a3=fmaf(q7.w, hv.w,a3);
                    hv=h4[8];  a0=fmaf(q8.x, hv.x,a0); a1=fmaf(q8.y, hv.y,a1); a2=fmaf(q8.z, hv.z,a2); a3=fmaf(q8.w, hv.w,a3);
                    hv=h4[9];  a0=fmaf(q9.x, hv.x,a0); a1=fmaf(q9.y, hv.y,a1); a2=fmaf(q9.z, hv.z,a2); a3=fmaf(q9.w, hv.w,a3);
                    hv=h4[10]; a0=fmaf(q10.x,hv.x,a0); a1=fmaf(q10.y,hv.y,a1); a2=fmaf(q10.z,hv.z,a2); a3=fmaf(q10.w,hv.w,a3);
                    hv=h4[11]; a0=fmaf(q11.x,hv.x,a0); a1=fmaf(q11.y,hv.y,a1); a2=fmaf(q11.z,hv.z,a2); a3=fmaf(q11.w,hv.w,a3);
                    float part = (a0 + a1) + (a2 + a3);
                    float* ph2 = ph_sh + ((tt & 1) ? G4 : 0);   // parity dbuf
                    if (halfx) ph2[g] = part;
                    BARL();
                    if (!halfx) xpd[(size_t)(t0 + tt) * G4 + dstoff] = part + ph2[g];
                }
                BARL();   // protect h_sh + ph slot reuse before next stage
            }
            __threadfence();
            __syncthreads();
            if (tid == 0) SIGNAL(&flag1[bidx], k + 1)
        }
    } else if (role == 2) {
        // =================== consumer: L1 scan ===================
        WLOADPIN(Whh1)

        float cU = c0v[HDIM + e];
        if (w0l) hs[e] = h0v[HDIM + e];
        __syncthreads();

#pragma unroll 1
        for (int k = 0; k < NCH; ++k) {
            if (tid == 0) {
                WAIT_GE(&flag1[bidx], k + 1)
                if (k >= 2) WAIT_GE(&flag3[bidx], k - 1)
            }
            __syncthreads();
            __threadfence();

            const float4* xq  = reinterpret_cast<const float4*>(
                xpbuf + ((size_t)bidx * 2 + (k & 1)) * TCH * G4) + e;
            float* h1p = h1buf + ((size_t)bidx * 2 + (k & 1)) * TCH * HDIM + e;

            float4 a0 = xq[0], a1 = xq[HDIM], a2 = xq[2 * HDIM], a3 = xq[3 * HDIM];

#pragma unroll 1
            for (int gI = 0; gI < TCH / 8; ++gI) {
                const float4* xg = xq + (size_t)gI * 8 * HDIM;
                float4 b0_, b1_, b2_, b3_;
                STEP2(0,    a0) b0_ = xg[4 * HDIM]; BARL();
                STEP2(HDIM, a1) b1_ = xg[5 * HDIM]; BARL();
                STEP2(0,    a2) b2_ = xg[6 * HDIM]; BARL();
                STEP2(HDIM, a3) b3_ = xg[7 * HDIM]; BARL();
                const float4* xn = xq + (size_t)((gI + 1 < TCH / 8) ? (gI + 1) * 8 : TCH - 8) * HDIM;
                STEP2(0,    b0_) a0 = xn[0];        BARL();
                STEP2(HDIM, b1_) a1 = xn[HDIM];     BARL();
                STEP2(0,    b2_) a2 = xn[2 * HDIM]; BARL();
                STEP2(HDIM, b3_) a3 = xn[3 * HDIM]; BARL();
            }
            __threadfence();
            __syncthreads();
            if (tid == 0) SIGNAL(&flag2[bidx], k + 1)
        }
    } else {
        // =================== head ===================
        const float hb = headb[0];
        float4 wv[24];
#pragma unroll
        for (int j = 0; j < 24; ++j) wv[j] = reinterpret_cast<const float4*>(headw)[j];

#pragma unroll 1
        for (int k = 0; k < NCH; ++k) {
            if (tid == 0) WAIT_GE(&flag2[bidx], k + 1)
            __syncthreads();
            __threadfence();

            const float* h1c = h1buf + ((size_t)bidx * 2 + (k & 1)) * TCH * HDIM;
            for (int t = tid; t < TCH; t += 768) {
                const float4* hp = reinterpret_cast<const float4*>(h1c + (size_t)t * HDIM);
                float s2 = 0.f;
#pragma unroll
                for (int j = 0; j < 24; ++j) {
                    float4 a = hp[j], b = wv[j];
                    s2 = fmaf(a.x, b.x, s2); s2 = fmaf(a.y, b.y, s2);
                    s2 = fmaf(a.z, b.z, s2); s2 = fmaf(a.w, b.w, s2);
                }
                out[(size_t)bidx * LSEQ + (size_t)k * TCH + t] = s2 + hb;
            }
            __threadfence();
            __syncthreads();
            if (tid == 0) SIGNAL(&flag3[bidx], k + 1)
        }
    }
}

// ---------------------------------------------------------------------------
extern "C" void kernel_launch(void* const* d_in, const int* in_sizes, int n_in,
                              void* d_out, int out_size, void* d_ws, size_t ws_size,
                              hipStream_t stream)
{
    const float* x     = (const float*)d_in[0];
    const float* Wih0  = (const float*)d_in[1];
    const float* Whh0  = (const float*)d_in[2];
    const float* b0    = (const float*)d_in[3];
    const float* Wih1  = (const float*)d_in[4];
    const float* Whh1  = (const float*)d_in[5];
    const float* b1    = (const float*)d_in[6];
    const float* h0    = (const float*)d_in[7];
    const float* c0    = (const float*)d_in[8];
    const float* headw = (const float*)d_in[9];
    const float* headb = (const float*)d_in[10];
    float* out = (float*)d_out;

    char* ws = (char*)d_ws;
    const size_t h0bytes = (size_t)BATCH * LSEQ * HDIM * sizeof(float);    // 100.7 MB
    const size_t xpbytes = (size_t)BATCH * 2 * TCH * G4 * sizeof(float);   // 25.2 MB
    const size_t h1bytes = (size_t)BATCH * 2 * TCH * HDIM * sizeof(float); // 6.3 MB

    float* h0buf = (float*)ws;
    float* xpbuf = (float*)(ws + h0bytes);
    float* h1buf = (float*)(ws + h0bytes + xpbytes);
    int*   flags = (int*)  (ws + h0bytes + xpbytes + h1bytes);

    init_flags<<<1, 64, 0, stream>>>(flags);
    lstm_pipe<<<32, 768, 0, stream>>>(x, Wih0, Whh0, b0, Wih1, Whh1, b1,
                                      h0, c0, headw, headb,
                                      h0buf, xpbuf, h1buf, flags, out);
}